// Round 1
// baseline (792.093 us; speedup 1.0000x reference)
//
#include <hip/hip_runtime.h>
#include <hip/hip_bf16.h>
#include <math.h>

#define A_TOK 4096
#define DDIM  1024
#define NEXP  8
#define FDIM  2816

typedef __bf16 bf16_t;
typedef __bf16 bf16x8 __attribute__((ext_vector_type(8)));
typedef float  f32x4  __attribute__((ext_vector_type(4)));

// ---------------- workspace layout ----------------
// [0,16384)        int   idx_a[4096]
// [16384,32768)    float gate_a[4096]
// [32768,32800)    int   count[8]
// [32800,32832)    int   cursor[8]
// [32832,32868)    int   offsets[9]
// [33280,49664)    int   perm[4096]
// [65536, +23068672)          bf16 mid_r[4096*2816]
// [65536+23068672, +23068672) bf16 mid_s[4096*2816]

// ---------------- router ----------------
__global__ void router_kernel(const float* __restrict__ x,
                              const float* __restrict__ router,
                              int* __restrict__ idx_a,
                              float* __restrict__ gate_a,
                              int* __restrict__ count)
{
    __shared__ float rT[NEXP][DDIM];           // transposed router, 32KB
    const int tid = threadIdx.x;
    for (int i = tid; i < DDIM * NEXP; i += 256) {
        int d = i >> 3, e = i & 7;
        rT[e][d] = router[i];
    }
    __syncthreads();

    const int wid = tid >> 6, lane = tid & 63;
    for (int it = 0; it < 4; ++it) {
        int t = blockIdx.x * 16 + wid * 4 + it;
        double s[NEXP];
#pragma unroll
        for (int e = 0; e < NEXP; ++e) s[e] = 0.0;
        for (int i = 0; i < DDIM / 64; ++i) {
            int d = lane + i * 64;
            float xv = x[(size_t)t * DDIM + d];
#pragma unroll
            for (int e = 0; e < NEXP; ++e)
                s[e] += (double)xv * (double)rT[e][d];
        }
#pragma unroll
        for (int e = 0; e < NEXP; ++e) {
#pragma unroll
            for (int off = 32; off > 0; off >>= 1)
                s[e] += __shfl_xor(s[e], off);
        }
        if (lane == 0) {
            int best = 0; double bv = s[0];
#pragma unroll
            for (int e = 1; e < NEXP; ++e)
                if (s[e] > bv) { bv = s[e]; best = e; }
            idx_a[t] = best;
            gate_a[t] = 1.0f / (1.0f + expf(-(float)bv));
            atomicAdd(&count[best], 1);
        }
    }
}

__global__ void scan_kernel(const int* __restrict__ count,
                            int* __restrict__ offsets)
{
    if (threadIdx.x == 0) {
        int acc = 0;
        for (int e = 0; e < NEXP; ++e) { offsets[e] = acc; acc += count[e]; }
        offsets[NEXP] = acc;
    }
}

__global__ void permute_kernel(const int* __restrict__ idx_a,
                               const int* __restrict__ offsets,
                               int* __restrict__ cursor,
                               int* __restrict__ perm)
{
    int t = blockIdx.x * 256 + threadIdx.x;
    if (t < A_TOK) {
        int e = idx_a[t];
        int pos = offsets[e] + atomicAdd(&cursor[e], 1);
        perm[pos] = t;
    }
}

// ---------------- GEMM config ----------------
#define BM 128
#define BN 64          // output cols per weight per block
#define BK 32
#define LSTR 40        // LDS K-stride (pad: 80B rows, 16B-aligned frags)

// GEMM1: mid = silu(A@W1) * (A@W3), A = gathered gate-scaled x rows (bf16 on the fly)
__global__ __launch_bounds__(256, 2)
void gemm1_kernel(const float* __restrict__ x,
                  const float* __restrict__ w1,
                  const float* __restrict__ w3,
                  const float* __restrict__ ws1,
                  const float* __restrict__ ws3,
                  const float* __restrict__ gate_a,
                  const int* __restrict__ perm,
                  const int* __restrict__ offsets,
                  bf16_t* __restrict__ mid_r,
                  bf16_t* __restrict__ mid_s)
{
    const int g  = blockIdx.z;           // 0..7 routed, 8 shared
    const int n0 = blockIdx.x * BN;
    int m0, mEnd;
    const float *pw1, *pw3;
    if (g < NEXP) {
        int s = offsets[g], e = offsets[g + 1];
        m0 = s + blockIdx.y * BM;
        if (m0 >= e) return;
        mEnd = e;
        pw1 = w1 + (size_t)g * DDIM * FDIM;
        pw3 = w3 + (size_t)g * DDIM * FDIM;
    } else {
        m0 = blockIdx.y * BM;
        mEnd = A_TOK;
        pw1 = ws1; pw3 = ws3;
    }

    __shared__ bf16_t sA[BM][LSTR];
    __shared__ bf16_t sW1[BN][LSTR];
    __shared__ bf16_t sW3[BN][LSTR];

    const int tid  = threadIdx.x;
    const int lane = tid & 63;
    const int wid  = tid >> 6;
    const int wm   = wid >> 1, wn = wid & 1;

    // A staging: row = tid/2, 16 floats starting at (tid&1)*16
    const int ar = tid >> 1;
    const int ac = (tid & 1) * 16;
    int p = m0 + ar;
    bool aValid = p < mEnd;
    int tok; float scale;
    if (g < NEXP) {
        tok   = aValid ? perm[p] : 0;
        scale = aValid ? gate_a[tok] : 0.0f;
    } else {
        tok   = p;
        scale = 1.0f;
    }
    const float* aSrc = x + (size_t)tok * DDIM + ac;

    // W staging: kk = tid/8 (0..31), nn = (tid&7)*8
    const int wkk = tid >> 3;
    const int wnn = (tid & 7) * 8;

    f32x4 acc1[4][2], acc3[4][2];
#pragma unroll
    for (int i = 0; i < 4; ++i)
#pragma unroll
        for (int j = 0; j < 2; ++j) {
            acc1[i][j] = (f32x4){0.f, 0.f, 0.f, 0.f};
            acc3[i][j] = (f32x4){0.f, 0.f, 0.f, 0.f};
        }

    for (int k0 = 0; k0 < DDIM; k0 += BK) {
        // ---- stage A (fp32 -> scaled bf16) ----
        float4 v[4];
#pragma unroll
        for (int q = 0; q < 4; ++q)
            v[q] = aValid ? *(const float4*)(aSrc + k0 + q * 4)
                          : make_float4(0.f, 0.f, 0.f, 0.f);
#pragma unroll
        for (int q = 0; q < 4; ++q) {
            sA[ar][ac + q * 4 + 0] = (bf16_t)(v[q].x * scale);
            sA[ar][ac + q * 4 + 1] = (bf16_t)(v[q].y * scale);
            sA[ar][ac + q * 4 + 2] = (bf16_t)(v[q].z * scale);
            sA[ar][ac + q * 4 + 3] = (bf16_t)(v[q].w * scale);
        }
        // ---- stage W1/W3 transposed ----
        {
            const float* s1 = pw1 + (size_t)(k0 + wkk) * FDIM + (n0 + wnn);
            float4 a0 = *(const float4*)s1;
            float4 a1 = *(const float4*)(s1 + 4);
            sW1[wnn + 0][wkk] = (bf16_t)a0.x;
            sW1[wnn + 1][wkk] = (bf16_t)a0.y;
            sW1[wnn + 2][wkk] = (bf16_t)a0.z;
            sW1[wnn + 3][wkk] = (bf16_t)a0.w;
            sW1[wnn + 4][wkk] = (bf16_t)a1.x;
            sW1[wnn + 5][wkk] = (bf16_t)a1.y;
            sW1[wnn + 6][wkk] = (bf16_t)a1.z;
            sW1[wnn + 7][wkk] = (bf16_t)a1.w;
            const float* s3 = pw3 + (size_t)(k0 + wkk) * FDIM + (n0 + wnn);
            float4 b0 = *(const float4*)s3;
            float4 b1 = *(const float4*)(s3 + 4);
            sW3[wnn + 0][wkk] = (bf16_t)b0.x;
            sW3[wnn + 1][wkk] = (bf16_t)b0.y;
            sW3[wnn + 2][wkk] = (bf16_t)b0.z;
            sW3[wnn + 3][wkk] = (bf16_t)b0.w;
            sW3[wnn + 4][wkk] = (bf16_t)b1.x;
            sW3[wnn + 5][wkk] = (bf16_t)b1.y;
            sW3[wnn + 6][wkk] = (bf16_t)b1.z;
            sW3[wnn + 7][wkk] = (bf16_t)b1.w;
        }
        __syncthreads();

        bf16x8 af[4], w1f[2], w3f[2];
#pragma unroll
        for (int mi = 0; mi < 4; ++mi)
            af[mi] = *(const bf16x8*)&sA[wm * 64 + mi * 16 + (lane & 15)][(lane >> 4) * 8];
#pragma unroll
        for (int ni = 0; ni < 2; ++ni) {
            w1f[ni] = *(const bf16x8*)&sW1[wn * 32 + ni * 16 + (lane & 15)][(lane >> 4) * 8];
            w3f[ni] = *(const bf16x8*)&sW3[wn * 32 + ni * 16 + (lane & 15)][(lane >> 4) * 8];
        }
#pragma unroll
        for (int mi = 0; mi < 4; ++mi)
#pragma unroll
            for (int ni = 0; ni < 2; ++ni) {
                acc1[mi][ni] = __builtin_amdgcn_mfma_f32_16x16x32_bf16(af[mi], w1f[ni], acc1[mi][ni], 0, 0, 0);
                acc3[mi][ni] = __builtin_amdgcn_mfma_f32_16x16x32_bf16(af[mi], w3f[ni], acc3[mi][ni], 0, 0, 0);
            }
        __syncthreads();
    }

    bf16_t* outBuf = (g < NEXP) ? mid_r : mid_s;
#pragma unroll
    for (int mi = 0; mi < 4; ++mi) {
#pragma unroll
        for (int r = 0; r < 4; ++r) {
            int row  = wm * 64 + mi * 16 + (lane >> 4) * 4 + r;
            int prow = m0 + row;
            if (prow < mEnd) {
#pragma unroll
                for (int ni = 0; ni < 2; ++ni) {
                    float h1 = acc1[mi][ni][r];
                    float h3 = acc3[mi][ni][r];
                    float vv = h1 / (1.0f + expf(-h1)) * h3;
                    int col = n0 + wn * 32 + ni * 16 + (lane & 15);
                    outBuf[(size_t)prow * FDIM + col] = (bf16_t)vv;
                }
            }
        }
    }
}

// GEMM2: out = mid @ W2  (shared: plain store; routed: scatter +=)
template <bool ROUTED>
__global__ __launch_bounds__(256, 2)
void gemm2_kernel(const bf16_t* __restrict__ mid,
                  const float* __restrict__ w2,
                  const int* __restrict__ perm,
                  const int* __restrict__ offsets,
                  float* __restrict__ out)
{
    const int n0 = blockIdx.x * BN;   // over D=1024
    int m0, mEnd;
    const float* pw;
    if (ROUTED) {
        int g = blockIdx.z;
        int s = offsets[g], e = offsets[g + 1];
        m0 = s + blockIdx.y * BM;
        if (m0 >= e) return;
        mEnd = e;
        pw = w2 + (size_t)g * FDIM * DDIM;
    } else {
        m0 = blockIdx.y * BM;
        mEnd = A_TOK;
        pw = w2;
    }

    __shared__ bf16_t sA[BM][LSTR];
    __shared__ bf16_t sW[BN][LSTR];

    const int tid  = threadIdx.x;
    const int lane = tid & 63;
    const int wid  = tid >> 6;
    const int wm   = wid >> 1, wn = wid & 1;

    const int ar = tid >> 1;
    const int ac = (tid & 1) * 16;
    const bool aValid = (m0 + ar) < mEnd;
    const bf16_t* aSrc = mid + (size_t)(m0 + ar) * FDIM + ac;

    const int wkk = tid >> 3;
    const int wnn = (tid & 7) * 8;

    f32x4 acc[4][2];
#pragma unroll
    for (int i = 0; i < 4; ++i)
#pragma unroll
        for (int j = 0; j < 2; ++j)
            acc[i][j] = (f32x4){0.f, 0.f, 0.f, 0.f};

    for (int k0 = 0; k0 < FDIM; k0 += BK) {
        // stage A (already bf16)
        bf16x8 a0, a1;
        if (aValid) {
            a0 = *(const bf16x8*)(aSrc + k0);
            a1 = *(const bf16x8*)(aSrc + k0 + 8);
        } else {
            a0 = (bf16x8)(bf16_t)0.f;
            a1 = (bf16x8)(bf16_t)0.f;
        }
        *(bf16x8*)&sA[ar][ac]     = a0;
        *(bf16x8*)&sA[ar][ac + 8] = a1;
        // stage W transposed (fp32 -> bf16)
        {
            const float* s1 = pw + (size_t)(k0 + wkk) * DDIM + (n0 + wnn);
            float4 b0 = *(const float4*)s1;
            float4 b1 = *(const float4*)(s1 + 4);
            sW[wnn + 0][wkk] = (bf16_t)b0.x;
            sW[wnn + 1][wkk] = (bf16_t)b0.y;
            sW[wnn + 2][wkk] = (bf16_t)b0.z;
            sW[wnn + 3][wkk] = (bf16_t)b0.w;
            sW[wnn + 4][wkk] = (bf16_t)b1.x;
            sW[wnn + 5][wkk] = (bf16_t)b1.y;
            sW[wnn + 6][wkk] = (bf16_t)b1.z;
            sW[wnn + 7][wkk] = (bf16_t)b1.w;
        }
        __syncthreads();

        bf16x8 af[4], wf[2];
#pragma unroll
        for (int mi = 0; mi < 4; ++mi)
            af[mi] = *(const bf16x8*)&sA[wm * 64 + mi * 16 + (lane & 15)][(lane >> 4) * 8];
#pragma unroll
        for (int ni = 0; ni < 2; ++ni)
            wf[ni] = *(const bf16x8*)&sW[wn * 32 + ni * 16 + (lane & 15)][(lane >> 4) * 8];
#pragma unroll
        for (int mi = 0; mi < 4; ++mi)
#pragma unroll
            for (int ni = 0; ni < 2; ++ni)
                acc[mi][ni] = __builtin_amdgcn_mfma_f32_16x16x32_bf16(af[mi], wf[ni], acc[mi][ni], 0, 0, 0);
        __syncthreads();
    }

#pragma unroll
    for (int mi = 0; mi < 4; ++mi) {
#pragma unroll
        for (int r = 0; r < 4; ++r) {
            int row  = wm * 64 + mi * 16 + (lane >> 4) * 4 + r;
            int prow = m0 + row;
            if (prow < mEnd) {
                int orow = ROUTED ? perm[prow] : prow;
#pragma unroll
                for (int ni = 0; ni < 2; ++ni) {
                    int col = n0 + wn * 32 + ni * 16 + (lane & 15);
                    float vv = acc[mi][ni][r];
                    if (ROUTED)
                        out[(size_t)orow * DDIM + col] += vv;
                    else
                        out[(size_t)orow * DDIM + col] = vv;
                }
            }
        }
    }
}

// ---------------- launch ----------------
extern "C" void kernel_launch(void* const* d_in, const int* in_sizes, int n_in,
                              void* d_out, int out_size, void* d_ws, size_t ws_size,
                              hipStream_t stream)
{
    const float* x      = (const float*)d_in[0];
    const float* router = (const float*)d_in[1];
    const float* w1     = (const float*)d_in[2];
    const float* w3     = (const float*)d_in[3];
    const float* w2     = (const float*)d_in[4];
    const float* ws1    = (const float*)d_in[5];
    const float* ws3    = (const float*)d_in[6];
    const float* ws2    = (const float*)d_in[7];
    float* out = (float*)d_out;

    char* ws = (char*)d_ws;
    int*   idx_a   = (int*)(ws + 0);
    float* gate_a  = (float*)(ws + 16384);
    int*   count   = (int*)(ws + 32768);
    int*   cursor  = (int*)(ws + 32800);
    int*   offsets = (int*)(ws + 32832);
    int*   perm    = (int*)(ws + 33280);
    bf16_t* mid_r  = (bf16_t*)(ws + 65536);
    bf16_t* mid_s  = (bf16_t*)(ws + 65536 + (size_t)A_TOK * FDIM * 2);

    // zero count/cursor/offsets
    hipMemsetAsync(ws + 32768, 0, 512, stream);

    router_kernel<<<256, 256, 0, stream>>>(x, router, idx_a, gate_a, count);
    scan_kernel<<<1, 64, 0, stream>>>(count, offsets);
    permute_kernel<<<16, 256, 0, stream>>>(idx_a, offsets, cursor, perm);

    gemm1_kernel<<<dim3(FDIM / BN, A_TOK / BM, NEXP + 1), 256, 0, stream>>>(
        x, w1, w3, ws1, ws3, gate_a, perm, offsets, mid_r, mid_s);

    gemm2_kernel<false><<<dim3(DDIM / BN, A_TOK / BM, 1), 256, 0, stream>>>(
        mid_s, ws2, perm, offsets, out);
    gemm2_kernel<true><<<dim3(DDIM / BN, A_TOK / BM, NEXP), 256, 0, stream>>>(
        mid_r, w2, perm, offsets, out);
}

// Round 2
// 538.744 us; speedup vs baseline: 1.4703x; 1.4703x over previous
//
#include <hip/hip_runtime.h>
#include <hip/hip_bf16.h>
#include <math.h>

#define A_TOK 4096
#define DDIM  1024
#define NEXP  8
#define FDIM  2816

typedef __bf16 bf16_t;
typedef __bf16 bf16x8 __attribute__((ext_vector_type(8)));
typedef __bf16 bf16x4 __attribute__((ext_vector_type(4)));
typedef float  f32x4  __attribute__((ext_vector_type(4)));

// ======================= workspace layout =======================
// common small:
//   [0,16384)      int   idx_a[4096]
//   [16384,32768)  float gate_a[4096]
//   [32768..]      count/cursor/offsets (memset 512B)
//   [33280,49664)  int   perm[4096]
// fast path (needs WS_NEED):
static constexpr size_t OFF_XS   = 65536;
static constexpr size_t OFF_XR   = OFF_XS   + (size_t)A_TOK * DDIM * 2;                 // 8388608
static constexpr size_t OFF_MIDS = OFF_XR   + (size_t)(A_TOK + 128) * DDIM * 2;         // 8650752
static constexpr size_t OFF_MIDR = OFF_MIDS + (size_t)A_TOK * FDIM * 2;                 // 23068672
static constexpr size_t OFF_W1T  = OFF_MIDR + (size_t)(A_TOK + 128) * FDIM * 2;         // 23789568
static constexpr size_t OFF_W3T  = OFF_W1T  + (size_t)NEXP * DDIM * FDIM * 2;           // 46137344
static constexpr size_t OFF_W2T  = OFF_W3T  + (size_t)NEXP * DDIM * FDIM * 2;
static constexpr size_t OFF_WS1T = OFF_W2T  + (size_t)NEXP * DDIM * FDIM * 2;
static constexpr size_t OFF_WS3T = OFF_WS1T + (size_t)DDIM * FDIM * 2;
static constexpr size_t OFF_WS2T = OFF_WS3T + (size_t)DDIM * FDIM * 2;
static constexpr size_t WS_NEED  = OFF_WS2T + (size_t)DDIM * FDIM * 2;   // ~209.5 MiB

// ======================= router =======================
__global__ void router_kernel(const float* __restrict__ x,
                              const float* __restrict__ router,
                              int* __restrict__ idx_a,
                              float* __restrict__ gate_a,
                              int* __restrict__ count)
{
    __shared__ float rT[NEXP][DDIM];
    const int tid = threadIdx.x;
    for (int i = tid; i < DDIM * NEXP; i += 256) {
        int d = i >> 3, e = i & 7;
        rT[e][d] = router[i];
    }
    __syncthreads();

    const int wid = tid >> 6, lane = tid & 63;
    for (int it = 0; it < 4; ++it) {
        int t = blockIdx.x * 16 + wid * 4 + it;
        double s[NEXP];
#pragma unroll
        for (int e = 0; e < NEXP; ++e) s[e] = 0.0;
        for (int i = 0; i < DDIM / 64; ++i) {
            int d = lane + i * 64;
            float xv = x[(size_t)t * DDIM + d];
#pragma unroll
            for (int e = 0; e < NEXP; ++e)
                s[e] += (double)xv * (double)rT[e][d];
        }
#pragma unroll
        for (int e = 0; e < NEXP; ++e) {
#pragma unroll
            for (int off = 32; off > 0; off >>= 1)
                s[e] += __shfl_xor(s[e], off);
        }
        if (lane == 0) {
            int best = 0; double bv = s[0];
#pragma unroll
            for (int e = 1; e < NEXP; ++e)
                if (s[e] > bv) { bv = s[e]; best = e; }
            idx_a[t] = best;
            gate_a[t] = 1.0f / (1.0f + expf(-(float)bv));
            atomicAdd(&count[best], 1);
        }
    }
}

__global__ void scan_kernel(const int* __restrict__ count,
                            int* __restrict__ offsets)
{
    if (threadIdx.x == 0) {
        int acc = 0;
        for (int e = 0; e < NEXP; ++e) { offsets[e] = acc; acc += count[e]; }
        offsets[NEXP] = acc;
    }
}

__global__ void permute_kernel(const int* __restrict__ idx_a,
                               const int* __restrict__ offsets,
                               int* __restrict__ cursor,
                               int* __restrict__ perm)
{
    int t = blockIdx.x * 256 + threadIdx.x;
    if (t < A_TOK) {
        int e = idx_a[t];
        int pos = offsets[e] + atomicAdd(&cursor[e], 1);
        perm[pos] = t;
    }
}

// ======================= prep kernels (fast path) =======================
// xs = bf16(x); xr[p] = bf16(x[perm[p]] * gate[perm[p]])
__global__ void prep_x_kernel(const float* __restrict__ x,
                              const float* __restrict__ gate_a,
                              const int* __restrict__ perm,
                              bf16_t* __restrict__ xs,
                              bf16_t* __restrict__ xr)
{
    const int p = blockIdx.x;
    const int d = threadIdx.x * 4;
    float4 v = *(const float4*)(x + (size_t)p * DDIM + d);
    bf16x4 o;
    o[0] = (bf16_t)v.x; o[1] = (bf16_t)v.y; o[2] = (bf16_t)v.z; o[3] = (bf16_t)v.w;
    *(bf16x4*)(xs + (size_t)p * DDIM + d) = o;

    const int tok = perm[p];
    const float g = gate_a[tok];
    float4 w = *(const float4*)(x + (size_t)tok * DDIM + d);
    bf16x4 o2;
    o2[0] = (bf16_t)(w.x * g); o2[1] = (bf16_t)(w.y * g);
    o2[2] = (bf16_t)(w.z * g); o2[3] = (bf16_t)(w.w * g);
    *(bf16x4*)(xr + (size_t)p * DDIM + d) = o2;
}

// src [R][C] fp32 -> dst [C][R] bf16, 64x64 tiles, z = matrix index
__global__ void tconv_kernel(const float* __restrict__ src,
                             bf16_t* __restrict__ dst, int R, int C)
{
    const size_t ms = (size_t)R * C;
    src += (size_t)blockIdx.z * ms;
    dst += (size_t)blockIdx.z * ms;
    const int r0 = blockIdx.y * 64, c0 = blockIdx.x * 64;

    __shared__ __align__(16) bf16_t t[64][72];
    const int tid = threadIdx.x;
    const int rl = tid >> 4;            // 0..15
    const int cl = (tid & 15) * 4;      // 0..60
#pragma unroll
    for (int i = 0; i < 4; ++i) {
        float4 v = *(const float4*)(src + (size_t)(r0 + rl + i * 16) * C + c0 + cl);
        t[cl + 0][rl + i * 16] = (bf16_t)v.x;
        t[cl + 1][rl + i * 16] = (bf16_t)v.y;
        t[cl + 2][rl + i * 16] = (bf16_t)v.z;
        t[cl + 3][rl + i * 16] = (bf16_t)v.w;
    }
    __syncthreads();
    const int cl2 = tid >> 3;           // 0..31
    const int rl2 = (tid & 7) * 8;      // 0..56
#pragma unroll
    for (int i = 0; i < 2; ++i) {
        int c = cl2 + i * 32;
        bf16x8 vv = *(const bf16x8*)&t[c][rl2];
        *(bf16x8*)(dst + (size_t)(c0 + c) * R + r0 + rl2) = vv;
    }
}

// ======================= bf16 GEMM machinery =======================
__device__ __forceinline__ void glds16(const bf16_t* g, bf16_t* l)
{
    __builtin_amdgcn_global_load_lds(
        (const __attribute__((address_space(1))) void*)g,
        (__attribute__((address_space(3))) void*)l, 16, 0, 0);
}

// stage 128 rows x 64 bf16 (128B/row), XOR-swizzled on 16B slots:
// LDS[row][slot] = global[row][slot ^ (row&7)]
__device__ __forceinline__ void stage_swz(const bf16_t* __restrict__ src,
                                          size_t stride, bf16_t* lds, int tid)
{
#pragma unroll
    for (int i = 0; i < 4; ++i) {
        int o = i * 256 + tid;          // 16B unit index 0..1023
        int row = o >> 3;
        int slot = o & 7;
        int srcSlot = slot ^ (row & 7);
        glds16(src + (size_t)row * stride + srcSlot * 8, lds + (size_t)o * 8);
    }
}

__device__ __forceinline__ int swz_off(int row, int g16)
{
    return row * 128 + ((g16 ^ (row & 7)) << 4);
}

// GEMM1: mid = silu(A@W1T^T) * (A@W3T^T); A 128 rows, N tile 128 (of F), K = D
__global__ __launch_bounds__(256, 2)
void gemm1_bf16(const bf16_t* __restrict__ xr, const bf16_t* __restrict__ xs,
                const bf16_t* __restrict__ w1T, const bf16_t* __restrict__ w3T,
                const bf16_t* __restrict__ ws1T, const bf16_t* __restrict__ ws3T,
                const int* __restrict__ offsets,
                bf16_t* __restrict__ mid_r, bf16_t* __restrict__ mid_s)
{
    const int g  = blockIdx.z;
    const int n0 = blockIdx.x * 128;
    int m0, mEnd;
    const bf16_t *pa, *pw1, *pw3;
    bf16_t* pout;
    if (g < NEXP) {
        int s = offsets[g], e = offsets[g + 1];
        m0 = s + blockIdx.y * 128;
        if (m0 >= e) return;
        mEnd = e;
        pa = xr;
        pw1 = w1T + (size_t)g * DDIM * FDIM;
        pw3 = w3T + (size_t)g * DDIM * FDIM;
        pout = mid_r;
    } else {
        m0 = blockIdx.y * 128;
        mEnd = A_TOK;
        pa = xs; pw1 = ws1T; pw3 = ws3T; pout = mid_s;
    }

    __shared__ __align__(16) bf16_t sA[128 * 64];
    __shared__ __align__(16) bf16_t sB1[128 * 64];
    __shared__ __align__(16) bf16_t sB3[128 * 64];

    const int tid  = threadIdx.x;
    const int lane = tid & 63;
    const int wid  = tid >> 6;
    const int wm   = wid >> 1, wn = wid & 1;
    const int fr   = lane & 15;
    const int fq   = lane >> 4;

    f32x4 acc1[4][4], acc3[4][4];
#pragma unroll
    for (int i = 0; i < 4; ++i)
#pragma unroll
        for (int j = 0; j < 4; ++j) {
            acc1[i][j] = (f32x4){0.f, 0.f, 0.f, 0.f};
            acc3[i][j] = (f32x4){0.f, 0.f, 0.f, 0.f};
        }

    const bf16_t* srcA  = pa  + (size_t)m0 * DDIM;
    const bf16_t* srcB1 = pw1 + (size_t)n0 * DDIM;
    const bf16_t* srcB3 = pw3 + (size_t)n0 * DDIM;

    for (int k0 = 0; k0 < DDIM; k0 += 64) {
        stage_swz(srcA  + k0, DDIM, sA,  tid);
        stage_swz(srcB1 + k0, DDIM, sB1, tid);
        stage_swz(srcB3 + k0, DDIM, sB3, tid);
        __syncthreads();

#pragma unroll
        for (int s = 0; s < 2; ++s) {
            const int kg = s * 4 + fq;
            bf16x8 af[4], b1f[4], b3f[4];
#pragma unroll
            for (int mi = 0; mi < 4; ++mi) {
                int r = wm * 64 + mi * 16 + fr;
                af[mi] = *(const bf16x8*)((const char*)sA + swz_off(r, kg));
            }
#pragma unroll
            for (int ni = 0; ni < 4; ++ni) {
                int r = wn * 64 + ni * 16 + fr;
                b1f[ni] = *(const bf16x8*)((const char*)sB1 + swz_off(r, kg));
                b3f[ni] = *(const bf16x8*)((const char*)sB3 + swz_off(r, kg));
            }
#pragma unroll
            for (int mi = 0; mi < 4; ++mi)
#pragma unroll
                for (int ni = 0; ni < 4; ++ni) {
                    acc1[mi][ni] = __builtin_amdgcn_mfma_f32_16x16x32_bf16(af[mi], b1f[ni], acc1[mi][ni], 0, 0, 0);
                    acc3[mi][ni] = __builtin_amdgcn_mfma_f32_16x16x32_bf16(af[mi], b3f[ni], acc3[mi][ni], 0, 0, 0);
                }
        }
        __syncthreads();
    }

#pragma unroll
    for (int mi = 0; mi < 4; ++mi) {
        int prow_b = m0 + wm * 64 + mi * 16 + fq * 4;
#pragma unroll
        for (int r = 0; r < 4; ++r) {
            int prow = prow_b + r;
            if (prow < mEnd) {
#pragma unroll
                for (int ni = 0; ni < 4; ++ni) {
                    float h1 = acc1[mi][ni][r];
                    float h3 = acc3[mi][ni][r];
                    float vv = h1 / (1.0f + __expf(-h1)) * h3;
                    int col = n0 + wn * 64 + ni * 16 + fr;
                    pout[(size_t)prow * FDIM + col] = (bf16_t)vv;
                }
            }
        }
    }
}

// GEMM2: out = mid @ W2 (w2T is [D][F] bf16). K = F, N tile 128 (of D).
template <bool ROUTED>
__global__ __launch_bounds__(256, 2)
void gemm2_bf16(const bf16_t* __restrict__ mid, const bf16_t* __restrict__ w2T,
                const int* __restrict__ perm, const int* __restrict__ offsets,
                float* __restrict__ out)
{
    const int n0 = blockIdx.x * 128;
    int m0, mEnd;
    const bf16_t* pb;
    if (ROUTED) {
        int g = blockIdx.z;
        int s = offsets[g], e = offsets[g + 1];
        m0 = s + blockIdx.y * 128;
        if (m0 >= e) return;
        mEnd = e;
        pb = w2T + (size_t)g * DDIM * FDIM;
    } else {
        m0 = blockIdx.y * 128;
        mEnd = A_TOK;
        pb = w2T;
    }

    __shared__ __align__(16) bf16_t sA[128 * 64];
    __shared__ __align__(16) bf16_t sB[128 * 64];

    const int tid  = threadIdx.x;
    const int lane = tid & 63;
    const int wid  = tid >> 6;
    const int wm   = wid >> 1, wn = wid & 1;
    const int fr   = lane & 15;
    const int fq   = lane >> 4;

    f32x4 acc[4][4];
#pragma unroll
    for (int i = 0; i < 4; ++i)
#pragma unroll
        for (int j = 0; j < 4; ++j)
            acc[i][j] = (f32x4){0.f, 0.f, 0.f, 0.f};

    const bf16_t* srcA = mid + (size_t)m0 * FDIM;
    const bf16_t* srcB = pb  + (size_t)n0 * FDIM;

    for (int k0 = 0; k0 < FDIM; k0 += 64) {
        stage_swz(srcA + k0, FDIM, sA, tid);
        stage_swz(srcB + k0, FDIM, sB, tid);
        __syncthreads();

#pragma unroll
        for (int s = 0; s < 2; ++s) {
            const int kg = s * 4 + fq;
            bf16x8 af[4], bf[4];
#pragma unroll
            for (int mi = 0; mi < 4; ++mi) {
                int r = wm * 64 + mi * 16 + fr;
                af[mi] = *(const bf16x8*)((const char*)sA + swz_off(r, kg));
            }
#pragma unroll
            for (int ni = 0; ni < 4; ++ni) {
                int r = wn * 64 + ni * 16 + fr;
                bf[ni] = *(const bf16x8*)((const char*)sB + swz_off(r, kg));
            }
#pragma unroll
            for (int mi = 0; mi < 4; ++mi)
#pragma unroll
                for (int ni = 0; ni < 4; ++ni)
                    acc[mi][ni] = __builtin_amdgcn_mfma_f32_16x16x32_bf16(af[mi], bf[ni], acc[mi][ni], 0, 0, 0);
        }
        __syncthreads();
    }

#pragma unroll
    for (int mi = 0; mi < 4; ++mi) {
        int prow_b = m0 + wm * 64 + mi * 16 + fq * 4;
#pragma unroll
        for (int r = 0; r < 4; ++r) {
            int prow = prow_b + r;
            if (prow < mEnd) {
                int orow = ROUTED ? perm[prow] : prow;
#pragma unroll
                for (int ni = 0; ni < 4; ++ni) {
                    int col = n0 + wn * 64 + ni * 16 + fr;
                    float vv = acc[mi][ni][r];
                    if (ROUTED)
                        out[(size_t)orow * DDIM + col] += vv;
                    else
                        out[(size_t)orow * DDIM + col] = vv;
                }
            }
        }
    }
}

// ======================= legacy (round-1) fallback =======================
#define BM 128
#define BN 64
#define BK 32
#define LSTR 40

__global__ __launch_bounds__(256, 2)
void gemm1_legacy(const float* __restrict__ x,
                  const float* __restrict__ w1,
                  const float* __restrict__ w3,
                  const float* __restrict__ ws1,
                  const float* __restrict__ ws3,
                  const float* __restrict__ gate_a,
                  const int* __restrict__ perm,
                  const int* __restrict__ offsets,
                  bf16_t* __restrict__ mid_r,
                  bf16_t* __restrict__ mid_s)
{
    const int g  = blockIdx.z;
    const int n0 = blockIdx.x * BN;
    int m0, mEnd;
    const float *pw1, *pw3;
    if (g < NEXP) {
        int s = offsets[g], e = offsets[g + 1];
        m0 = s + blockIdx.y * BM;
        if (m0 >= e) return;
        mEnd = e;
        pw1 = w1 + (size_t)g * DDIM * FDIM;
        pw3 = w3 + (size_t)g * DDIM * FDIM;
    } else {
        m0 = blockIdx.y * BM;
        mEnd = A_TOK;
        pw1 = ws1; pw3 = ws3;
    }

    __shared__ bf16_t sA[BM][LSTR];
    __shared__ bf16_t sW1[BN][LSTR];
    __shared__ bf16_t sW3[BN][LSTR];

    const int tid  = threadIdx.x;
    const int lane = tid & 63;
    const int wid  = tid >> 6;
    const int wm   = wid >> 1, wn = wid & 1;

    const int ar = tid >> 1;
    const int ac = (tid & 1) * 16;
    int p = m0 + ar;
    bool aValid = p < mEnd;
    int tok; float scale;
    if (g < NEXP) {
        tok   = aValid ? perm[p] : 0;
        scale = aValid ? gate_a[tok] : 0.0f;
    } else {
        tok   = p;
        scale = 1.0f;
    }
    const float* aSrc = x + (size_t)tok * DDIM + ac;

    const int wkk = tid >> 3;
    const int wnn = (tid & 7) * 8;

    f32x4 acc1[4][2], acc3[4][2];
#pragma unroll
    for (int i = 0; i < 4; ++i)
#pragma unroll
        for (int j = 0; j < 2; ++j) {
            acc1[i][j] = (f32x4){0.f, 0.f, 0.f, 0.f};
            acc3[i][j] = (f32x4){0.f, 0.f, 0.f, 0.f};
        }

    for (int k0 = 0; k0 < DDIM; k0 += BK) {
        float4 v[4];
#pragma unroll
        for (int q = 0; q < 4; ++q)
            v[q] = aValid ? *(const float4*)(aSrc + k0 + q * 4)
                          : make_float4(0.f, 0.f, 0.f, 0.f);
#pragma unroll
        for (int q = 0; q < 4; ++q) {
            sA[ar][ac + q * 4 + 0] = (bf16_t)(v[q].x * scale);
            sA[ar][ac + q * 4 + 1] = (bf16_t)(v[q].y * scale);
            sA[ar][ac + q * 4 + 2] = (bf16_t)(v[q].z * scale);
            sA[ar][ac + q * 4 + 3] = (bf16_t)(v[q].w * scale);
        }
        {
            const float* s1 = pw1 + (size_t)(k0 + wkk) * FDIM + (n0 + wnn);
            float4 a0 = *(const float4*)s1;
            float4 a1 = *(const float4*)(s1 + 4);
            sW1[wnn + 0][wkk] = (bf16_t)a0.x;
            sW1[wnn + 1][wkk] = (bf16_t)a0.y;
            sW1[wnn + 2][wkk] = (bf16_t)a0.z;
            sW1[wnn + 3][wkk] = (bf16_t)a0.w;
            sW1[wnn + 4][wkk] = (bf16_t)a1.x;
            sW1[wnn + 5][wkk] = (bf16_t)a1.y;
            sW1[wnn + 6][wkk] = (bf16_t)a1.z;
            sW1[wnn + 7][wkk] = (bf16_t)a1.w;
            const float* s3 = pw3 + (size_t)(k0 + wkk) * FDIM + (n0 + wnn);
            float4 b0 = *(const float4*)s3;
            float4 b1 = *(const float4*)(s3 + 4);
            sW3[wnn + 0][wkk] = (bf16_t)b0.x;
            sW3[wnn + 1][wkk] = (bf16_t)b0.y;
            sW3[wnn + 2][wkk] = (bf16_t)b0.z;
            sW3[wnn + 3][wkk] = (bf16_t)b0.w;
            sW3[wnn + 4][wkk] = (bf16_t)b1.x;
            sW3[wnn + 5][wkk] = (bf16_t)b1.y;
            sW3[wnn + 6][wkk] = (bf16_t)b1.z;
            sW3[wnn + 7][wkk] = (bf16_t)b1.w;
        }
        __syncthreads();

        bf16x8 af[4], w1f[2], w3f[2];
#pragma unroll
        for (int mi = 0; mi < 4; ++mi)
            af[mi] = *(const bf16x8*)&sA[wm * 64 + mi * 16 + (lane & 15)][(lane >> 4) * 8];
#pragma unroll
        for (int ni = 0; ni < 2; ++ni) {
            w1f[ni] = *(const bf16x8*)&sW1[wn * 32 + ni * 16 + (lane & 15)][(lane >> 4) * 8];
            w3f[ni] = *(const bf16x8*)&sW3[wn * 32 + ni * 16 + (lane & 15)][(lane >> 4) * 8];
        }
#pragma unroll
        for (int mi = 0; mi < 4; ++mi)
#pragma unroll
            for (int ni = 0; ni < 2; ++ni) {
                acc1[mi][ni] = __builtin_amdgcn_mfma_f32_16x16x32_bf16(af[mi], w1f[ni], acc1[mi][ni], 0, 0, 0);
                acc3[mi][ni] = __builtin_amdgcn_mfma_f32_16x16x32_bf16(af[mi], w3f[ni], acc3[mi][ni], 0, 0, 0);
            }
        __syncthreads();
    }

    bf16_t* outBuf = (g < NEXP) ? mid_r : mid_s;
#pragma unroll
    for (int mi = 0; mi < 4; ++mi) {
#pragma unroll
        for (int r = 0; r < 4; ++r) {
            int row  = wm * 64 + mi * 16 + (lane >> 4) * 4 + r;
            int prow = m0 + row;
            if (prow < mEnd) {
#pragma unroll
                for (int ni = 0; ni < 2; ++ni) {
                    float h1 = acc1[mi][ni][r];
                    float h3 = acc3[mi][ni][r];
                    float vv = h1 / (1.0f + expf(-h1)) * h3;
                    int col = n0 + wn * 32 + ni * 16 + (lane & 15);
                    outBuf[(size_t)prow * FDIM + col] = (bf16_t)vv;
                }
            }
        }
    }
}

template <bool ROUTED>
__global__ __launch_bounds__(256, 2)
void gemm2_legacy(const bf16_t* __restrict__ mid,
                  const float* __restrict__ w2,
                  const int* __restrict__ perm,
                  const int* __restrict__ offsets,
                  float* __restrict__ out)
{
    const int n0 = blockIdx.x * BN;
    int m0, mEnd;
    const float* pw;
    if (ROUTED) {
        int g = blockIdx.z;
        int s = offsets[g], e = offsets[g + 1];
        m0 = s + blockIdx.y * BM;
        if (m0 >= e) return;
        mEnd = e;
        pw = w2 + (size_t)g * FDIM * DDIM;
    } else {
        m0 = blockIdx.y * BM;
        mEnd = A_TOK;
        pw = w2;
    }

    __shared__ bf16_t sA[BM][LSTR];
    __shared__ bf16_t sW[BN][LSTR];

    const int tid  = threadIdx.x;
    const int lane = tid & 63;
    const int wid  = tid >> 6;
    const int wm   = wid >> 1, wn = wid & 1;

    const int ar = tid >> 1;
    const int ac = (tid & 1) * 16;
    const bool aValid = (m0 + ar) < mEnd;
    const bf16_t* aSrc = mid + (size_t)(m0 + ar) * FDIM + ac;

    const int wkk = tid >> 3;
    const int wnn = (tid & 7) * 8;

    f32x4 acc[4][2];
#pragma unroll
    for (int i = 0; i < 4; ++i)
#pragma unroll
        for (int j = 0; j < 2; ++j)
            acc[i][j] = (f32x4){0.f, 0.f, 0.f, 0.f};

    for (int k0 = 0; k0 < FDIM; k0 += BK) {
        bf16x8 a0, a1;
        if (aValid) {
            a0 = *(const bf16x8*)(aSrc + k0);
            a1 = *(const bf16x8*)(aSrc + k0 + 8);
        } else {
            a0 = (bf16x8)(bf16_t)0.f;
            a1 = (bf16x8)(bf16_t)0.f;
        }
        *(bf16x8*)&sA[ar][ac]     = a0;
        *(bf16x8*)&sA[ar][ac + 8] = a1;
        {
            const float* s1 = pw + (size_t)(k0 + wkk) * DDIM + (n0 + wnn);
            float4 b0 = *(const float4*)s1;
            float4 b1 = *(const float4*)(s1 + 4);
            sW[wnn + 0][wkk] = (bf16_t)b0.x;
            sW[wnn + 1][wkk] = (bf16_t)b0.y;
            sW[wnn + 2][wkk] = (bf16_t)b0.z;
            sW[wnn + 3][wkk] = (bf16_t)b0.w;
            sW[wnn + 4][wkk] = (bf16_t)b1.x;
            sW[wnn + 5][wkk] = (bf16_t)b1.y;
            sW[wnn + 6][wkk] = (bf16_t)b1.z;
            sW[wnn + 7][wkk] = (bf16_t)b1.w;
        }
        __syncthreads();

        bf16x8 af[4], wf[2];
#pragma unroll
        for (int mi = 0; mi < 4; ++mi)
            af[mi] = *(const bf16x8*)&sA[wm * 64 + mi * 16 + (lane & 15)][(lane >> 4) * 8];
#pragma unroll
        for (int ni = 0; ni < 2; ++ni)
            wf[ni] = *(const bf16x8*)&sW[wn * 32 + ni * 16 + (lane & 15)][(lane >> 4) * 8];
#pragma unroll
        for (int mi = 0; mi < 4; ++mi)
#pragma unroll
            for (int ni = 0; ni < 2; ++ni)
                acc[mi][ni] = __builtin_amdgcn_mfma_f32_16x16x32_bf16(af[mi], wf[ni], acc[mi][ni], 0, 0, 0);
        __syncthreads();
    }

#pragma unroll
    for (int mi = 0; mi < 4; ++mi) {
#pragma unroll
        for (int r = 0; r < 4; ++r) {
            int row  = wm * 64 + mi * 16 + (lane >> 4) * 4 + r;
            int prow = m0 + row;
            if (prow < mEnd) {
                int orow = ROUTED ? perm[prow] : prow;
#pragma unroll
                for (int ni = 0; ni < 2; ++ni) {
                    int col = n0 + wn * 32 + ni * 16 + (lane & 15);
                    float vv = acc[mi][ni][r];
                    if (ROUTED)
                        out[(size_t)orow * DDIM + col] += vv;
                    else
                        out[(size_t)orow * DDIM + col] = vv;
                }
            }
        }
    }
}

// ======================= launch =======================
extern "C" void kernel_launch(void* const* d_in, const int* in_sizes, int n_in,
                              void* d_out, int out_size, void* d_ws, size_t ws_size,
                              hipStream_t stream)
{
    const float* x      = (const float*)d_in[0];
    const float* router = (const float*)d_in[1];
    const float* w1     = (const float*)d_in[2];
    const float* w3     = (const float*)d_in[3];
    const float* w2     = (const float*)d_in[4];
    const float* ws1    = (const float*)d_in[5];
    const float* ws3    = (const float*)d_in[6];
    const float* ws2    = (const float*)d_in[7];
    float* out = (float*)d_out;

    char* ws = (char*)d_ws;
    int*   idx_a   = (int*)(ws + 0);
    float* gate_a  = (float*)(ws + 16384);
    int*   count   = (int*)(ws + 32768);
    int*   cursor  = (int*)(ws + 32800);
    int*   offsets = (int*)(ws + 32832);
    int*   perm    = (int*)(ws + 33280);

    hipMemsetAsync(ws + 32768, 0, 512, stream);
    router_kernel<<<256, 256, 0, stream>>>(x, router, idx_a, gate_a, count);
    scan_kernel<<<1, 64, 0, stream>>>(count, offsets);
    permute_kernel<<<16, 256, 0, stream>>>(idx_a, offsets, cursor, perm);

    if (ws_size >= WS_NEED) {
        bf16_t* xs    = (bf16_t*)(ws + OFF_XS);
        bf16_t* xr    = (bf16_t*)(ws + OFF_XR);
        bf16_t* mid_s = (bf16_t*)(ws + OFF_MIDS);
        bf16_t* mid_r = (bf16_t*)(ws + OFF_MIDR);
        bf16_t* w1T   = (bf16_t*)(ws + OFF_W1T);
        bf16_t* w3T   = (bf16_t*)(ws + OFF_W3T);
        bf16_t* w2T   = (bf16_t*)(ws + OFF_W2T);
        bf16_t* ws1T  = (bf16_t*)(ws + OFF_WS1T);
        bf16_t* ws3T  = (bf16_t*)(ws + OFF_WS3T);
        bf16_t* ws2T  = (bf16_t*)(ws + OFF_WS2T);

        prep_x_kernel<<<A_TOK, 256, 0, stream>>>(x, gate_a, perm, xs, xr);
        // w1/w3/ws1/ws3: [1024][2816] -> [2816][1024]
        tconv_kernel<<<dim3(44, 16, 8), 256, 0, stream>>>(w1, w1T, DDIM, FDIM);
        tconv_kernel<<<dim3(44, 16, 8), 256, 0, stream>>>(w3, w3T, DDIM, FDIM);
        tconv_kernel<<<dim3(44, 16, 1), 256, 0, stream>>>(ws1, ws1T, DDIM, FDIM);
        tconv_kernel<<<dim3(44, 16, 1), 256, 0, stream>>>(ws3, ws3T, DDIM, FDIM);

        gemm1_bf16<<<dim3(FDIM / 128, 32, NEXP + 1), 256, 0, stream>>>(
            xr, xs, w1T, w3T, ws1T, ws3T, offsets, mid_r, mid_s);

        // w2/ws2: [2816][1024] -> [1024][2816]
        tconv_kernel<<<dim3(16, 44, 8), 256, 0, stream>>>(w2, w2T, FDIM, DDIM);
        tconv_kernel<<<dim3(16, 44, 1), 256, 0, stream>>>(ws2, ws2T, FDIM, DDIM);

        gemm2_bf16<false><<<dim3(DDIM / 128, 32, 1), 256, 0, stream>>>(
            mid_s, ws2T, perm, offsets, out);
        gemm2_bf16<true><<<dim3(DDIM / 128, 32, NEXP), 256, 0, stream>>>(
            mid_r, w2T, perm, offsets, out);
    } else {
        bf16_t* mid_r = (bf16_t*)(ws + 65536);
        bf16_t* mid_s = (bf16_t*)(ws + 65536 + (size_t)A_TOK * FDIM * 2);

        gemm1_legacy<<<dim3(FDIM / BN, A_TOK / BM, NEXP + 1), 256, 0, stream>>>(
            x, w1, w3, ws1, ws3, gate_a, perm, offsets, mid_r, mid_s);
        gemm2_legacy<false><<<dim3(DDIM / BN, A_TOK / BM, 1), 256, 0, stream>>>(
            mid_s, ws2, perm, offsets, out);
        gemm2_legacy<true><<<dim3(DDIM / BN, A_TOK / BM, NEXP), 256, 0, stream>>>(
            mid_r, w2, perm, offsets, out);
    }
}

// Round 3
// 387.675 us; speedup vs baseline: 2.0432x; 1.3897x over previous
//
#include <hip/hip_runtime.h>
#include <hip/hip_bf16.h>
#include <math.h>

#define A_TOK 4096
#define DDIM  1024
#define NEXP  8
#define FDIM  2816

typedef __bf16 bf16_t;
typedef __bf16 bf16x8 __attribute__((ext_vector_type(8)));
typedef __bf16 bf16x4 __attribute__((ext_vector_type(4)));
typedef float  f32x4  __attribute__((ext_vector_type(4)));

// ======================= workspace layout =======================
//   [0,16384)      int   idx_a[4096]
//   [16384,32768)  float gate_a[4096]
//   [32832,32868)  int   offsets[9]
//   [33280,49664)  int   perm[4096]
static constexpr size_t OFF_XS   = 65536;
static constexpr size_t OFF_XR   = OFF_XS   + (size_t)A_TOK * DDIM * 2;
static constexpr size_t OFF_MIDS = OFF_XR   + (size_t)(A_TOK + 128) * DDIM * 2;
static constexpr size_t OFF_MIDR = OFF_MIDS + (size_t)A_TOK * FDIM * 2;
static constexpr size_t OFF_W1T  = OFF_MIDR + (size_t)(A_TOK + 128) * FDIM * 2;
static constexpr size_t OFF_W3T  = OFF_W1T  + (size_t)NEXP * DDIM * FDIM * 2;
static constexpr size_t OFF_W2T  = OFF_W3T  + (size_t)NEXP * DDIM * FDIM * 2;
static constexpr size_t OFF_WS1T = OFF_W2T  + (size_t)NEXP * DDIM * FDIM * 2;
static constexpr size_t OFF_WS3T = OFF_WS1T + (size_t)DDIM * FDIM * 2;
static constexpr size_t OFF_WS2T = OFF_WS3T + (size_t)DDIM * FDIM * 2;
static constexpr size_t WS_NEED  = OFF_WS2T + (size_t)DDIM * FDIM * 2;   // ~209.5 MiB
// Round-2 verified ws_size >= WS_NEED (fast path executed); legacy path removed.

// ======================= router: scores =======================
// 1024 blocks x 256 thr; 1 token per wave; no atomics; f64 accumulation.
__global__ __launch_bounds__(256)
void score_kernel(const float* __restrict__ x,
                  const float* __restrict__ router,
                  int* __restrict__ idx_a,
                  float* __restrict__ gate_a)
{
    __shared__ float rT[NEXP][DDIM];           // 32 KB, transposed router
    const int tid = threadIdx.x;
    for (int i = tid; i < DDIM * NEXP; i += 256)
        rT[i & 7][i >> 3] = router[i];
    __syncthreads();

    const int wid = tid >> 6, lane = tid & 63;
    const int t = blockIdx.x * 4 + wid;
    const float* xr = x + (size_t)t * DDIM;

    double s[NEXP];
#pragma unroll
    for (int e = 0; e < NEXP; ++e) s[e] = 0.0;
#pragma unroll
    for (int i = 0; i < DDIM / 64; ++i) {
        int d = i * 64 + lane;
        float xv = xr[d];
#pragma unroll
        for (int e = 0; e < NEXP; ++e)
            s[e] += (double)xv * (double)rT[e][d];
    }
#pragma unroll
    for (int e = 0; e < NEXP; ++e) {
#pragma unroll
        for (int off = 32; off > 0; off >>= 1)
            s[e] += __shfl_xor(s[e], off);
    }
    if (lane == 0) {
        int best = 0; double bv = s[0];
#pragma unroll
        for (int e = 1; e < NEXP; ++e)
            if (s[e] > bv) { bv = s[e]; best = e; }
        idx_a[t] = best;
        gate_a[t] = 1.0f / (1.0f + expf(-(float)bv));
    }
}

// ======================= fused count + scan + scatter =======================
// single block, 1024 threads
__global__ __launch_bounds__(1024)
void perm_kernel(const int* __restrict__ idx_a,
                 int* __restrict__ offsets,
                 int* __restrict__ perm)
{
    __shared__ int cnt[NEXP];
    __shared__ int base[NEXP];
    const int tid = threadIdx.x;
    if (tid < NEXP) cnt[tid] = 0;
    __syncthreads();

    int e[4];
#pragma unroll
    for (int j = 0; j < 4; ++j) {
        e[j] = idx_a[j * 1024 + tid];
        atomicAdd(&cnt[e[j]], 1);
    }
    __syncthreads();
    if (tid == 0) {
        int acc = 0;
#pragma unroll
        for (int k = 0; k < NEXP; ++k) {
            base[k] = acc; offsets[k] = acc; acc += cnt[k];
        }
        offsets[NEXP] = acc;
    }
    __syncthreads();
#pragma unroll
    for (int j = 0; j < 4; ++j) {
        int t = j * 1024 + tid;
        int pos = atomicAdd(&base[e[j]], 1);
        perm[pos] = t;
    }
}

// ======================= prep kernels =======================
__global__ void prep_x_kernel(const float* __restrict__ x,
                              const float* __restrict__ gate_a,
                              const int* __restrict__ perm,
                              bf16_t* __restrict__ xs,
                              bf16_t* __restrict__ xr)
{
    const int p = blockIdx.x;
    const int d = threadIdx.x * 4;
    float4 v = *(const float4*)(x + (size_t)p * DDIM + d);
    bf16x4 o;
    o[0] = (bf16_t)v.x; o[1] = (bf16_t)v.y; o[2] = (bf16_t)v.z; o[3] = (bf16_t)v.w;
    *(bf16x4*)(xs + (size_t)p * DDIM + d) = o;

    const int tok = perm[p];
    const float g = gate_a[tok];
    float4 w = *(const float4*)(x + (size_t)tok * DDIM + d);
    bf16x4 o2;
    o2[0] = (bf16_t)(w.x * g); o2[1] = (bf16_t)(w.y * g);
    o2[2] = (bf16_t)(w.z * g); o2[3] = (bf16_t)(w.w * g);
    *(bf16x4*)(xr + (size_t)p * DDIM + d) = o2;
}

// transpose+convert core: src [R][C] fp32 -> dst [C][R] bf16, one 64x64 tile
__device__ __forceinline__ void tconv_tile(const float* __restrict__ src,
                                           bf16_t* __restrict__ dst,
                                           int R, int C, int r0, int c0)
{
    __shared__ __align__(16) bf16_t t[64][72];
    const int tid = threadIdx.x;
    const int rl = tid >> 4;
    const int cl = (tid & 15) * 4;
#pragma unroll
    for (int i = 0; i < 4; ++i) {
        float4 v = *(const float4*)(src + (size_t)(r0 + rl + i * 16) * C + c0 + cl);
        t[cl + 0][rl + i * 16] = (bf16_t)v.x;
        t[cl + 1][rl + i * 16] = (bf16_t)v.y;
        t[cl + 2][rl + i * 16] = (bf16_t)v.z;
        t[cl + 3][rl + i * 16] = (bf16_t)v.w;
    }
    __syncthreads();
    const int cl2 = tid >> 3;
    const int rl2 = (tid & 7) * 8;
#pragma unroll
    for (int i = 0; i < 2; ++i) {
        int c = cl2 + i * 32;
        bf16x8 vv = *(const bf16x8*)&t[c][rl2];
        *(bf16x8*)(dst + (size_t)(c0 + c) * R + r0 + rl2) = vv;
    }
}

// phase A: z 0..7 -> w1[e], 8..15 -> w3[e], 16 -> ws1, 17 -> ws3 (R=1024, C=2816)
__global__ void tconvA_kernel(const float* __restrict__ w1, const float* __restrict__ w3,
                              const float* __restrict__ ws1, const float* __restrict__ ws3,
                              bf16_t* __restrict__ w1T, bf16_t* __restrict__ w3T,
                              bf16_t* __restrict__ ws1T, bf16_t* __restrict__ ws3T)
{
    const int z = blockIdx.z;
    const size_t ms = (size_t)DDIM * FDIM;
    const float* src; bf16_t* dst;
    if (z < 8)       { src = w1 + (size_t)z * ms;       dst = w1T + (size_t)z * ms; }
    else if (z < 16) { src = w3 + (size_t)(z - 8) * ms; dst = w3T + (size_t)(z - 8) * ms; }
    else if (z == 16){ src = ws1;                        dst = ws1T; }
    else             { src = ws3;                        dst = ws3T; }
    tconv_tile(src, dst, DDIM, FDIM, blockIdx.y * 64, blockIdx.x * 64);
}

// phase B: z 0..7 -> w2[e], 8 -> ws2 (R=2816, C=1024)
__global__ void tconvB_kernel(const float* __restrict__ w2, const float* __restrict__ ws2,
                              bf16_t* __restrict__ w2T, bf16_t* __restrict__ ws2T)
{
    const int z = blockIdx.z;
    const size_t ms = (size_t)DDIM * FDIM;
    const float* src; bf16_t* dst;
    if (z < 8) { src = w2 + (size_t)z * ms; dst = w2T + (size_t)z * ms; }
    else       { src = ws2;                  dst = ws2T; }
    tconv_tile(src, dst, FDIM, DDIM, blockIdx.y * 64, blockIdx.x * 64);
}

// ======================= bf16 GEMM machinery =======================
__device__ __forceinline__ void glds16(const bf16_t* g, bf16_t* l)
{
    __builtin_amdgcn_global_load_lds(
        (const __attribute__((address_space(1))) void*)g,
        (__attribute__((address_space(3))) void*)l, 16, 0, 0);
}

// stage 128 rows x 64 bf16 (128B/row), XOR-swizzled on 16B slots:
// LDS[row][slot] = global[row][slot ^ (row&7)]
__device__ __forceinline__ void stage_swz(const bf16_t* __restrict__ src,
                                          size_t stride, bf16_t* lds, int tid)
{
#pragma unroll
    for (int i = 0; i < 4; ++i) {
        int o = i * 256 + tid;
        int row = o >> 3;
        int slot = o & 7;
        int srcSlot = slot ^ (row & 7);
        glds16(src + (size_t)row * stride + srcSlot * 8, lds + (size_t)o * 8);
    }
}

__device__ __forceinline__ int swz_off(int row, int g16)
{
    return row * 128 + ((g16 ^ (row & 7)) << 4);
}

// GEMM1: mid = silu(A@W1T^T) * (A@W3T^T)
__global__ __launch_bounds__(256, 2)
void gemm1_bf16(const bf16_t* __restrict__ xr, const bf16_t* __restrict__ xs,
                const bf16_t* __restrict__ w1T, const bf16_t* __restrict__ w3T,
                const bf16_t* __restrict__ ws1T, const bf16_t* __restrict__ ws3T,
                const int* __restrict__ offsets,
                bf16_t* __restrict__ mid_r, bf16_t* __restrict__ mid_s)
{
    const int g  = blockIdx.z;
    const int n0 = blockIdx.x * 128;
    int m0, mEnd;
    const bf16_t *pa, *pw1, *pw3;
    bf16_t* pout;
    if (g < NEXP) {
        int s = offsets[g], e = offsets[g + 1];
        m0 = s + blockIdx.y * 128;
        if (m0 >= e) return;
        mEnd = e;
        pa = xr;
        pw1 = w1T + (size_t)g * DDIM * FDIM;
        pw3 = w3T + (size_t)g * DDIM * FDIM;
        pout = mid_r;
    } else {
        m0 = blockIdx.y * 128;
        mEnd = A_TOK;
        pa = xs; pw1 = ws1T; pw3 = ws3T; pout = mid_s;
    }

    __shared__ __align__(16) bf16_t sA[128 * 64];
    __shared__ __align__(16) bf16_t sB1[128 * 64];
    __shared__ __align__(16) bf16_t sB3[128 * 64];

    const int tid  = threadIdx.x;
    const int lane = tid & 63;
    const int wid  = tid >> 6;
    const int wm   = wid >> 1, wn = wid & 1;
    const int fr   = lane & 15;
    const int fq   = lane >> 4;

    f32x4 acc1[4][4], acc3[4][4];
#pragma unroll
    for (int i = 0; i < 4; ++i)
#pragma unroll
        for (int j = 0; j < 4; ++j) {
            acc1[i][j] = (f32x4){0.f, 0.f, 0.f, 0.f};
            acc3[i][j] = (f32x4){0.f, 0.f, 0.f, 0.f};
        }

    const bf16_t* srcA  = pa  + (size_t)m0 * DDIM;
    const bf16_t* srcB1 = pw1 + (size_t)n0 * DDIM;
    const bf16_t* srcB3 = pw3 + (size_t)n0 * DDIM;

    for (int k0 = 0; k0 < DDIM; k0 += 64) {
        stage_swz(srcA  + k0, DDIM, sA,  tid);
        stage_swz(srcB1 + k0, DDIM, sB1, tid);
        stage_swz(srcB3 + k0, DDIM, sB3, tid);
        __syncthreads();

#pragma unroll
        for (int s = 0; s < 2; ++s) {
            const int kg = s * 4 + fq;
            bf16x8 af[4], b1f[4], b3f[4];
#pragma unroll
            for (int mi = 0; mi < 4; ++mi) {
                int r = wm * 64 + mi * 16 + fr;
                af[mi] = *(const bf16x8*)((const char*)sA + swz_off(r, kg));
            }
#pragma unroll
            for (int ni = 0; ni < 4; ++ni) {
                int r = wn * 64 + ni * 16 + fr;
                b1f[ni] = *(const bf16x8*)((const char*)sB1 + swz_off(r, kg));
                b3f[ni] = *(const bf16x8*)((const char*)sB3 + swz_off(r, kg));
            }
#pragma unroll
            for (int mi = 0; mi < 4; ++mi)
#pragma unroll
                for (int ni = 0; ni < 4; ++ni) {
                    acc1[mi][ni] = __builtin_amdgcn_mfma_f32_16x16x32_bf16(af[mi], b1f[ni], acc1[mi][ni], 0, 0, 0);
                    acc3[mi][ni] = __builtin_amdgcn_mfma_f32_16x16x32_bf16(af[mi], b3f[ni], acc3[mi][ni], 0, 0, 0);
                }
        }
        __syncthreads();
    }

#pragma unroll
    for (int mi = 0; mi < 4; ++mi) {
        int prow_b = m0 + wm * 64 + mi * 16 + fq * 4;
#pragma unroll
        for (int r = 0; r < 4; ++r) {
            int prow = prow_b + r;
            if (prow < mEnd) {
#pragma unroll
                for (int ni = 0; ni < 4; ++ni) {
                    float h1 = acc1[mi][ni][r];
                    float h3 = acc3[mi][ni][r];
                    float vv = h1 / (1.0f + __expf(-h1)) * h3;
                    int col = n0 + wn * 64 + ni * 16 + fr;
                    pout[(size_t)prow * FDIM + col] = (bf16_t)vv;
                }
            }
        }
    }
}

// GEMM2: out = mid @ W2
template <bool ROUTED>
__global__ __launch_bounds__(256, 2)
void gemm2_bf16(const bf16_t* __restrict__ mid, const bf16_t* __restrict__ w2T,
                const int* __restrict__ perm, const int* __restrict__ offsets,
                float* __restrict__ out)
{
    const int n0 = blockIdx.x * 128;
    int m0, mEnd;
    const bf16_t* pb;
    if (ROUTED) {
        int g = blockIdx.z;
        int s = offsets[g], e = offsets[g + 1];
        m0 = s + blockIdx.y * 128;
        if (m0 >= e) return;
        mEnd = e;
        pb = w2T + (size_t)g * DDIM * FDIM;
    } else {
        m0 = blockIdx.y * 128;
        mEnd = A_TOK;
        pb = w2T;
    }

    __shared__ __align__(16) bf16_t sA[128 * 64];
    __shared__ __align__(16) bf16_t sB[128 * 64];

    const int tid  = threadIdx.x;
    const int lane = tid & 63;
    const int wid  = tid >> 6;
    const int wm   = wid >> 1, wn = wid & 1;
    const int fr   = lane & 15;
    const int fq   = lane >> 4;

    f32x4 acc[4][4];
#pragma unroll
    for (int i = 0; i < 4; ++i)
#pragma unroll
        for (int j = 0; j < 4; ++j)
            acc[i][j] = (f32x4){0.f, 0.f, 0.f, 0.f};

    const bf16_t* srcA = mid + (size_t)m0 * FDIM;
    const bf16_t* srcB = pb  + (size_t)n0 * FDIM;

    for (int k0 = 0; k0 < FDIM; k0 += 64) {
        stage_swz(srcA + k0, FDIM, sA, tid);
        stage_swz(srcB + k0, FDIM, sB, tid);
        __syncthreads();

#pragma unroll
        for (int s = 0; s < 2; ++s) {
            const int kg = s * 4 + fq;
            bf16x8 af[4], bf[4];
#pragma unroll
            for (int mi = 0; mi < 4; ++mi) {
                int r = wm * 64 + mi * 16 + fr;
                af[mi] = *(const bf16x8*)((const char*)sA + swz_off(r, kg));
            }
#pragma unroll
            for (int ni = 0; ni < 4; ++ni) {
                int r = wn * 64 + ni * 16 + fr;
                bf[ni] = *(const bf16x8*)((const char*)sB + swz_off(r, kg));
            }
#pragma unroll
            for (int mi = 0; mi < 4; ++mi)
#pragma unroll
                for (int ni = 0; ni < 4; ++ni)
                    acc[mi][ni] = __builtin_amdgcn_mfma_f32_16x16x32_bf16(af[mi], bf[ni], acc[mi][ni], 0, 0, 0);
        }
        __syncthreads();
    }

#pragma unroll
    for (int mi = 0; mi < 4; ++mi) {
        int prow_b = m0 + wm * 64 + mi * 16 + fq * 4;
#pragma unroll
        for (int r = 0; r < 4; ++r) {
            int prow = prow_b + r;
            if (prow < mEnd) {
                int orow = ROUTED ? perm[prow] : prow;
#pragma unroll
                for (int ni = 0; ni < 4; ++ni) {
                    int col = n0 + wn * 64 + ni * 16 + fr;
                    float vv = acc[mi][ni][r];
                    if (ROUTED)
                        out[(size_t)orow * DDIM + col] += vv;
                    else
                        out[(size_t)orow * DDIM + col] = vv;
                }
            }
        }
    }
}

// ======================= launch =======================
extern "C" void kernel_launch(void* const* d_in, const int* in_sizes, int n_in,
                              void* d_out, int out_size, void* d_ws, size_t ws_size,
                              hipStream_t stream)
{
    const float* x      = (const float*)d_in[0];
    const float* router = (const float*)d_in[1];
    const float* w1     = (const float*)d_in[2];
    const float* w3     = (const float*)d_in[3];
    const float* w2     = (const float*)d_in[4];
    const float* ws1    = (const float*)d_in[5];
    const float* ws3    = (const float*)d_in[6];
    const float* ws2    = (const float*)d_in[7];
    float* out = (float*)d_out;

    char* ws = (char*)d_ws;
    int*   idx_a   = (int*)(ws + 0);
    float* gate_a  = (float*)(ws + 16384);
    int*   offsets = (int*)(ws + 32832);
    int*   perm    = (int*)(ws + 33280);

    bf16_t* xs    = (bf16_t*)(ws + OFF_XS);
    bf16_t* xr    = (bf16_t*)(ws + OFF_XR);
    bf16_t* mid_s = (bf16_t*)(ws + OFF_MIDS);
    bf16_t* mid_r = (bf16_t*)(ws + OFF_MIDR);
    bf16_t* w1T   = (bf16_t*)(ws + OFF_W1T);
    bf16_t* w3T   = (bf16_t*)(ws + OFF_W3T);
    bf16_t* w2T   = (bf16_t*)(ws + OFF_W2T);
    bf16_t* ws1T  = (bf16_t*)(ws + OFF_WS1T);
    bf16_t* ws3T  = (bf16_t*)(ws + OFF_WS3T);
    bf16_t* ws2T  = (bf16_t*)(ws + OFF_WS2T);

    score_kernel<<<A_TOK / 4, 256, 0, stream>>>(x, router, idx_a, gate_a);
    perm_kernel<<<1, 1024, 0, stream>>>(idx_a, offsets, perm);

    prep_x_kernel<<<A_TOK, 256, 0, stream>>>(x, gate_a, perm, xs, xr);
    tconvA_kernel<<<dim3(FDIM / 64, DDIM / 64, 18), 256, 0, stream>>>(
        w1, w3, ws1, ws3, w1T, w3T, ws1T, ws3T);

    gemm1_bf16<<<dim3(FDIM / 128, 32, NEXP + 1), 256, 0, stream>>>(
        xr, xs, w1T, w3T, ws1T, ws3T, offsets, mid_r, mid_s);

    tconvB_kernel<<<dim3(DDIM / 64, FDIM / 64, 9), 256, 0, stream>>>(
        w2, ws2, w2T, ws2T);

    gemm2_bf16<false><<<dim3(DDIM / 128, 32, 1), 256, 0, stream>>>(
        mid_s, ws2T, perm, offsets, out);
    gemm2_bf16<true><<<dim3(DDIM / 128, 32, NEXP), 256, 0, stream>>>(
        mid_r, w2T, perm, offsets, out);
}